// Round 26
// baseline (46.759 us; speedup 1.0000x reference)
//
#include <hip/hip_runtime.h>
#include <hip/hip_bf16.h>

#define NB   4
#define CIN  64
#define COUT 64
#define HH   160
#define WW   160
#define HW   (HH * WW)

// halo tile: 2x32 output tile, rate in [1,3) =>
// rows 2rr-3 .. 2rr+4 (8), cols 32cc-3 .. 32cc+34 (38).
#define RT   8
#define CT   38
#define RS   72              // record stride in shorts (144 B: 64ch + 8 pad)
#define RSB  (RS * 2)        // record stride in bytes (144)
#define HIN_SHORTS (RT * CT * RS)   // 21888 shorts = 43776 B

typedef __attribute__((ext_vector_type(8))) short bf16x8;   // 8 bf16 = 4 VGPR
typedef __attribute__((ext_vector_type(4))) float f32x4;
typedef __attribute__((ext_vector_type(2))) float f32x2;
typedef __attribute__((ext_vector_type(4))) unsigned int u32x4;

static __device__ __forceinline__ short f2bf(float v) {
    return __builtin_bit_cast(short, __float2bfloat16(v));
}

// ---------------------------------------------------------------------------
// Pre-pass: weight [O][C][3][3] f32 -> wtf in exact A-fragment order:
// wtf[t][ks][mt][lane][j]; frag (t,ks,mt) = contiguous 1 KB, lane reads 16 B.
// ---------------------------------------------------------------------------
__global__ void wtf_kernel(const float* __restrict__ w, short* __restrict__ wtf) {
    int i = blockIdx.x * 256 + threadIdx.x;   // 9*2*4*64*8 = 36864
    if (i < 36864) {
        const int j  = i & 7;
        const int l  = (i >> 3) & 63;
        const int mt = (i >> 9) & 3;
        const int ks = (i >> 11) & 1;
        const int t  = i >> 12;
        const int o  = 16 * mt + (l & 15);
        const int c  = 32 * ks + 8 * (l >> 4) + j;
        wtf[i] = f2bf(w[(o * CIN + c) * 9 + t]);
    }
}

// Blend 8 channels (4 dwords of packed bf16 pairs) + 4 MFMA rank-updates.
static __device__ __forceinline__ void consume_tap(
    const u32x4 v00, const u32x4 v01, const u32x4 v10, const u32x4 v11,
    const float c00, const float c01, const float c10, const float c11,
    const bf16x8 wf0, const bf16x8 wf1, const bf16x8 wf2, const bf16x8 wf3,
    f32x4 acc[4])
{
    union { bf16x8 v; unsigned u[4]; } pf;
#pragma unroll
    for (int wd = 0; wd < 4; ++wd) {
        f32x2 s;
        {
            const unsigned u0 = v00[wd];
            const f32x2 xv = { __builtin_bit_cast(float, u0 << 16),
                               __builtin_bit_cast(float, u0 & 0xffff0000u) };
            s = c00 * xv;
        }
        {
            const unsigned u0 = v01[wd];
            const f32x2 xv = { __builtin_bit_cast(float, u0 << 16),
                               __builtin_bit_cast(float, u0 & 0xffff0000u) };
            s += c01 * xv;
        }
        {
            const unsigned u0 = v10[wd];
            const f32x2 xv = { __builtin_bit_cast(float, u0 << 16),
                               __builtin_bit_cast(float, u0 & 0xffff0000u) };
            s += c10 * xv;
        }
        {
            const unsigned u0 = v11[wd];
            const f32x2 xv = { __builtin_bit_cast(float, u0 << 16),
                               __builtin_bit_cast(float, u0 & 0xffff0000u) };
            s += c11 * xv;
        }
        unsigned r;
        asm("v_cvt_pk_bf16_f32 %0, %1, %2" : "=v"(r) : "v"(s.x), "v"(s.y));
        pf.u[wd] = r;
    }
    acc[0] = __builtin_amdgcn_mfma_f32_16x16x32_bf16(wf0, pf.v, acc[0], 0, 0, 0);
    acc[1] = __builtin_amdgcn_mfma_f32_16x16x32_bf16(wf1, pf.v, acc[1], 0, 0, 0);
    acc[2] = __builtin_amdgcn_mfma_f32_16x16x32_bf16(wf2, pf.v, acc[2], 0, 0, 0);
    acc[3] = __builtin_amdgcn_mfma_f32_16x16x32_bf16(wf3, pf.v, acc[3], 0, 0, 0);
}

// ---------------------------------------------------------------------------
// Main kernel (2x32 tile + STRIP-PAIRED WEIGHT REUSE + packed staging):
// block = 2x32 output tile (1600 blocks), 4 waves = 2 rows x 2 K-halves.
// Each wave computes TWO 16-px strips; the 4 weight A-frags per tap are
// loaded ONCE and feed 8 MFMAs (R25 diagnosis: 460 MB of per-strip weight
// re-reads ~ 13 us of L2 BW; pairing halves it). Staging: NCHW f32 read
// directly (R25), converted via v_cvt_pk_bf16_f32 pairs and written as
// b128 (8 writes/record vs 64 b16 — the 144 B-stride 8-way bank conflict
// now costs per-16B not per-2B; SQ_LDS_BANK_CONFLICT was 2.55 M).
// Hoisted separable geometry per strip (R23-verified incl. >=0 checks).
// LDS: 43,776 halo + 17,408 red = 61,184 B.
// ---------------------------------------------------------------------------
__global__ __launch_bounds__(256, 2) void pdconv_pair_kernel(
    const float* __restrict__ in,        // [B][CIN][H][W] f32 (original)
    const short* __restrict__ wtf,       // frag-ordered weights bf16
    const float* __restrict__ rate_map,  // [B][1][H][W] f32
    const float* __restrict__ bias,      // [COUT] f32
    float* __restrict__ out)             // [B][COUT][H][W] f32
{
    __shared__ short hin[HIN_SHORTS];    // 43,776 B
    __shared__ float red[2][2][64][17];  // [strip][row] 17,408 B

    const int tid  = threadIdx.x;
    const int wave = tid >> 6;
    const int lane = tid & 63;
    const int px   = lane & 15;
    const int g    = lane >> 4;
    const int r    = wave >> 1;          // row within the 2-row tile
    const int th   = wave & 1;           // channel half (ks)

    // XCD-bijective swizzle (1600 % 8 == 0)
    const int cpx = gridDim.x >> 3;                     // 200
    const int bid = (blockIdx.x & 7) * cpx + (blockIdx.x >> 3);

    // bid -> (b, row-pair rr, col-block cc): 80 pairs x 5 col-blocks / image
    const int b   = bid / 400;
    const int rem = bid - b * 400;
    const int rr  = rem / 5;
    const int cc  = rem - rr * 5;
    const int oy  = 2 * rr - 3;
    const int ox  = 32 * cc - 3;

    // ---- fused staging: NCHW f32 -> LDS bf16 halo, packed b128 writes ----
    const float* ibase = in + (size_t)b * CIN * HW;
#pragma unroll
    for (int it = 0; it < 2; ++it) {
        const int rec = it * 256 + tid;              // 304 records
        if (rec < RT * CT) {
            const int ty = rec / CT;
            const int tx = rec - ty * CT;
            const int gy = min(max(oy + ty, 0), HH - 1);
            const int gx = min(max(ox + tx, 0), WW - 1);
            const float* src = ibase + gy * WW + gx;
            short* dst = hin + rec * RS;
#pragma unroll
            for (int co = 0; co < 8; ++co) {
                union { u32x4 v; unsigned u[4]; } pk;
#pragma unroll
                for (int q = 0; q < 4; ++q) {
                    const float lo = src[(size_t)(co * 8 + 2 * q)     * HW];
                    const float hi = src[(size_t)(co * 8 + 2 * q + 1) * HW];
                    unsigned pr;
                    asm("v_cvt_pk_bf16_f32 %0, %1, %2"
                        : "=v"(pr) : "v"(lo), "v"(hi));
                    pk.u[q] = pr;
                }
                *(u32x4*)(dst + co * 8) = pk.v;
            }
        }
    }

    // ---- per-wave: row = 2rr + r; strips at cols 32cc and 32cc+16 ----
    const int row  = 2 * rr + r;
    const int col0 = 32 * cc;
    const float rate0 = rate_map[b * HW + row * WW + col0 + px];
    const float rate1 = rate_map[b * HW + row * WW + col0 + 16 + px];
    const float fy  = (float)row;
    const float fx0 = (float)(col0 + px);
    const float fx1 = (float)(col0 + 16 + px);

    // ---- hoisted separable geometry per strip (constant indexing only) ----
    float wy0v[2][3], wy1v[2][3], wx0v[2][3], wx1v[2][3];
    int   ryb[2][3], txb[2][3];
#pragma unroll
    for (int s = 0; s < 2; ++s) {
        const float rate = s ? rate1 : rate0;
        const float fx   = s ? fx1   : fx0;
#pragma unroll
        for (int k = 0; k < 3; ++k) {
            const float sy  = fy + (float)(k - 1) * rate;
            const float y0f = floorf(sy);
            const float wy  = sy - y0f;
            const int   y0  = (int)y0f;
            const float vy0 = (y0 >= 0 && y0 < HH) ? 1.0f : 0.0f;
            const float vy1 = (y0 + 1 >= 0 && y0 + 1 < HH) ? 1.0f : 0.0f;
            wy0v[s][k] = (1.0f - wy) * vy0;
            wy1v[s][k] = wy * vy1;
            ryb[s][k]  = (y0 - oy) * (CT * RSB);

            const float sx  = fx + (float)(k - 1) * rate;
            const float x0f = floorf(sx);
            const float wx  = sx - x0f;
            const int   x0  = (int)x0f;
            const float vx0 = (x0 >= 0 && x0 < WW) ? 1.0f : 0.0f;
            const float vx1 = (x0 + 1 >= 0 && x0 + 1 < WW) ? 1.0f : 0.0f;
            wx0v[s][k] = (1.0f - wx) * vx0;
            wx1v[s][k] = wx * vx1;
            txb[s][k]  = (x0 - ox) * RSB;
        }
    }

    const int chan_off = 32 * th + 8 * g;                // shorts
    const short* wtb = wtf + lane * 8;                   // + frag*512

    f32x4 acc0[4], acc1[4];
#pragma unroll
    for (int mt = 0; mt < 4; ++mt) {
        acc0[mt] = (f32x4){0.f, 0.f, 0.f, 0.f};
        acc1[mt] = (f32x4){0.f, 0.f, 0.f, 0.f};
    }

    __syncthreads();           // halo staged

    // per tap: 4 weight frags loaded ONCE feed both strips (8 MFMA)
#define DO_TAP(T) do {                                                       \
    const int ky = (T) / 3, kx = (T) - 3 * ((T) / 3);   /* constants */      \
    const short* wb = wtb + (size_t)(((T) * 2 + th) * 4) * 512;              \
    const bf16x8 wf0 = *(const bf16x8*)(wb);                                 \
    const bf16x8 wf1 = *(const bf16x8*)(wb + 512);                           \
    const bf16x8 wf2 = *(const bf16x8*)(wb + 1024);                          \
    const bf16x8 wf3 = *(const bf16x8*)(wb + 1536);                          \
    {   /* strip 0 */                                                        \
        const float c00 = wy0v[0][ky] * wx0v[0][kx];                         \
        const float c01 = wy0v[0][ky] * wx1v[0][kx];                         \
        const float c10 = wy1v[0][ky] * wx0v[0][kx];                         \
        const float c11 = wy1v[0][ky] * wx1v[0][kx];                         \
        const short* hk = (const short*)((const char*)hin                    \
                          + ryb[0][ky] + txb[0][kx]) + chan_off;             \
        const u32x4 v00 = *(const u32x4*)(hk);                               \
        const u32x4 v01 = *(const u32x4*)(hk + RS);                          \
        const u32x4 v10 = *(const u32x4*)(hk + CT * RS);                     \
        const u32x4 v11 = *(const u32x4*)(hk + (CT + 1) * RS);               \
        consume_tap(v00, v01, v10, v11, c00, c01, c10, c11,                  \
                    wf0, wf1, wf2, wf3, acc0);                               \
    }                                                                        \
    {   /* strip 1 (same weights) */                                         \
        const float c00 = wy0v[1][ky] * wx0v[1][kx];                         \
        const float c01 = wy0v[1][ky] * wx1v[1][kx];                         \
        const float c10 = wy1v[1][ky] * wx0v[1][kx];                         \
        const float c11 = wy1v[1][ky] * wx1v[1][kx];                         \
        const short* hk = (const short*)((const char*)hin                    \
                          + ryb[1][ky] + txb[1][kx]) + chan_off;             \
        const u32x4 v00 = *(const u32x4*)(hk);                               \
        const u32x4 v01 = *(const u32x4*)(hk + RS);                          \
        const u32x4 v10 = *(const u32x4*)(hk + CT * RS);                     \
        const u32x4 v11 = *(const u32x4*)(hk + (CT + 1) * RS);               \
        consume_tap(v00, v01, v10, v11, c00, c01, c10, c11,                  \
                    wf0, wf1, wf2, wf3, acc1);                               \
    }                                                                        \
} while (0)

    DO_TAP(0); DO_TAP(1); DO_TAP(2); DO_TAP(3); DO_TAP(4);
    DO_TAP(5); DO_TAP(6); DO_TAP(7); DO_TAP(8);
#undef DO_TAP

    // ---- channel-half reduction (both strips) ----
    if (th == 1) {
#pragma unroll
        for (int mt = 0; mt < 4; ++mt)
#pragma unroll
            for (int j = 0; j < 4; ++j) {
                red[0][r][lane][4 * mt + j] = acc0[mt][j];
                red[1][r][lane][4 * mt + j] = acc1[mt][j];
            }
    }
    __syncthreads();
    if (th == 0) {
        float* op0 = out + (size_t)b * COUT * HW + row * WW + col0 + px;
        float* op1 = op0 + 16;
#pragma unroll
        for (int mt = 0; mt < 4; ++mt) {
            const f32x4 bv = *(const f32x4*)(bias + 16 * mt + 4 * g);
#pragma unroll
            for (int j = 0; j < 4; ++j) {
                const int o = 16 * mt + 4 * g + j;
                op0[(size_t)o * HW] = acc0[mt][j] + red[0][r][lane][4 * mt + j] + bv[j];
                op1[(size_t)o * HW] = acc1[mt][j] + red[1][r][lane][4 * mt + j] + bv[j];
            }
        }
    }
}

// ---------------------------------------------------------------------------
// Fallback (round-7 NCHW path) if ws_size is too small.
// ---------------------------------------------------------------------------
__global__ void wt2_kernel(const float* __restrict__ w, short* __restrict__ wt2) {
    int i = blockIdx.x * 256 + threadIdx.x;
    if (i < 9 * COUT * CIN) {
        int c = i & 63, o = (i >> 6) & 63, t = i >> 12;
        wt2[i] = f2bf(w[(o * CIN + c) * 9 + t]);
    }
}

__global__ __launch_bounds__(256) void pdconv_mfma_kernel(
    const float* __restrict__ in, const short* __restrict__ wt2,
    const float* __restrict__ rate_map, const float* __restrict__ bias,
    float* __restrict__ out)
{
    const int tid = threadIdx.x, wave = tid >> 6, lane = tid & 63;
    const int px = lane & 15, g = lane >> 4;
    const int cpx = gridDim.x >> 3;
    const int bid = (blockIdx.x & 7) * cpx + (blockIdx.x >> 3);
    const int base = bid * 64 + wave * 16;
    const int b = base / HW, pix0 = base - b * HW;
    const int y = pix0 / WW, x0 = pix0 - y * WW, x = x0 + px;
    const float rate = rate_map[base + px];
    const float fy = (float)y, fx = (float)x;
    f32x4 acc[4];
#pragma unroll
    for (int mt = 0; mt < 4; ++mt) acc[mt] = (f32x4){0.f, 0.f, 0.f, 0.f};
    const float* img  = in + (size_t)b * CIN * HW;
    const float* imgg = img + (size_t)g * 8 * HW;
#pragma unroll 1
    for (int t = 0; t < 9; ++t) {
        const int ky = t / 3, kx = t - 3 * ky;
        const float sy = fy + (float)(ky - 1) * rate;
        const float sx = fx + (float)(kx - 1) * rate;
        const float y0f = floorf(sy), x0f = floorf(sx);
        const float wy = sy - y0f, wx = sx - x0f;
        const int y0 = (int)y0f, x0i = (int)x0f, y1 = y0 + 1, x1 = x0i + 1;
        const float omwy = 1.0f - wy, omwx = 1.0f - wx;
        const float vy0 = (y0 >= 0 && y0 < HH) ? 1.0f : 0.0f;
        const float vy1 = (y1 >= 0 && y1 < HH) ? 1.0f : 0.0f;
        const float vx0 = (x0i >= 0 && x0i < WW) ? 1.0f : 0.0f;
        const float vx1 = (x1 >= 0 && x1 < WW) ? 1.0f : 0.0f;
        const float c00 = omwy * omwx * vy0 * vx0, c01 = omwy * wx * vy0 * vx1;
        const float c10 = wy * omwx * vy1 * vx0,  c11 = wy * wx * vy1 * vx1;
        const int cy0 = min(max(y0, 0), HH - 1), cy1 = min(max(y1, 0), HH - 1);
        const int cx0 = min(max(x0i, 0), WW - 1), cx1 = min(max(x1, 0), WW - 1);
        const int i00 = cy0 * WW + cx0, i01 = cy0 * WW + cx1;
        const int i10 = cy1 * WW + cx0, i11 = cy1 * WW + cx1;
#pragma unroll
        for (int ks = 0; ks < 2; ++ks) {
            bf16x8 wf[4];
#pragma unroll
            for (int mt = 0; mt < 4; ++mt)
                wf[mt] = *(const bf16x8*)(wt2 +
                          ((t * COUT + 16 * mt + px) * CIN + 32 * ks + 8 * g));
            float a[8];
#pragma unroll
            for (int j = 0; j < 8; ++j) {
                const float* ch = imgg + (size_t)(32 * ks + j) * HW;
                a[j] = c00 * ch[i00] + c01 * ch[i01] + c10 * ch[i10] + c11 * ch[i11];
            }
            union { bf16x8 v; short s[8]; } pf;
#pragma unroll
            for (int j = 0; j < 8; ++j) pf.s[j] = f2bf(a[j]);
#pragma unroll
            for (int mt = 0; mt < 4; ++mt)
                acc[mt] = __builtin_amdgcn_mfma_f32_16x16x32_bf16(
                              wf[mt], pf.v, acc[mt], 0, 0, 0);
        }
    }
    float* op = out + (size_t)b * COUT * HW + pix0 + px;
#pragma unroll
    for (int mt = 0; mt < 4; ++mt)
#pragma unroll
        for (int r = 0; r < 4; ++r) {
            const int o = 16 * mt + 4 * g + r;
            op[(size_t)o * HW] = acc[mt][r] + bias[o];
        }
}

extern "C" void kernel_launch(void* const* d_in, const int* in_sizes, int n_in,
                              void* d_out, int out_size, void* d_ws, size_t ws_size,
                              hipStream_t stream) {
    (void)in_sizes; (void)n_in; (void)out_size;
    const float* in   = (const float*)d_in[0];
    const float* w    = (const float*)d_in[1];
    const float* rm   = (const float*)d_in[2];
    const float* bias = (const float*)d_in[3];
    float* out = (float*)d_out;

    const size_t WTF_BYTES = 36864 * sizeof(short);   // 73,728

    if (ws_size >= WTF_BYTES) {
        short* wtf = (short*)d_ws;
        hipLaunchKernelGGL(wtf_kernel, dim3(144), dim3(256), 0, stream, w, wtf);
        const int nblocks = NB * 80 * 5;   // 1600: 2x32 tiles
        hipLaunchKernelGGL(pdconv_pair_kernel, dim3(nblocks), dim3(256), 0,
                           stream, in, wtf, rm, bias, out);
    } else {
        short* wt2 = (short*)d_ws;   // 73,728 B
        hipLaunchKernelGGL(wt2_kernel, dim3(144), dim3(256), 0, stream, w, wt2);
        hipLaunchKernelGGL(pdconv_mfma_kernel, dim3((NB * HW) / 64), dim3(256),
                           0, stream, in, wt2, rm, bias, out);
    }
}

// Round 27
// 41.910 us; speedup vs baseline: 1.1157x; 1.1157x over previous
//
#include <hip/hip_runtime.h>
#include <hip/hip_bf16.h>

#define NB   4
#define CIN  64
#define COUT 64
#define HH   160
#define WW   160
#define HW   (HH * WW)

// halo tile: 4x16 output tile, rate in [1,3) =>
// rows 4rr-3 .. 4rr+6 (10), cols 16cc-3 .. 16cc+18 (22).
#define RT   10
#define CT   22
#define RS   72              // record stride in shorts (144 B: 64ch + 8 pad)
#define RSB  (RS * 2)        // record stride in bytes (144)
#define HIN_SHORTS (RT * CT * RS)   // 15840 shorts = 31680 B

typedef __attribute__((ext_vector_type(8))) short bf16x8;   // 8 bf16 = 4 VGPR
typedef __attribute__((ext_vector_type(4))) float f32x4;
typedef __attribute__((ext_vector_type(2))) float f32x2;
typedef __attribute__((ext_vector_type(4))) unsigned int u32x4;

static __device__ __forceinline__ short f2bf(float v) {
    return __builtin_bit_cast(short, __float2bfloat16(v));
}

// ---------------------------------------------------------------------------
// Pre-pass: weight [O][C][3][3] f32 -> wtf in exact A-fragment order:
// wtf[t][ks][mt][lane][j]; frag (t,ks,mt) = contiguous 1 KB, lane reads 16 B.
// ---------------------------------------------------------------------------
__global__ void wtf_kernel(const float* __restrict__ w, short* __restrict__ wtf) {
    int i = blockIdx.x * 256 + threadIdx.x;   // 9*2*4*64*8 = 36864
    if (i < 36864) {
        const int j  = i & 7;
        const int l  = (i >> 3) & 63;
        const int mt = (i >> 9) & 3;
        const int ks = (i >> 11) & 1;
        const int t  = i >> 12;
        const int o  = 16 * mt + (l & 15);
        const int c  = 32 * ks + 8 * (l >> 4) + j;
        wtf[i] = f2bf(w[(o * CIN + c) * 9 + t]);
    }
}

// Blend 8 channels (4 dwords of packed bf16 pairs) + 4 MFMA rank-updates.
static __device__ __forceinline__ void consume_tap(
    const u32x4 v00, const u32x4 v01, const u32x4 v10, const u32x4 v11,
    const float c00, const float c01, const float c10, const float c11,
    const bf16x8 wf0, const bf16x8 wf1, const bf16x8 wf2, const bf16x8 wf3,
    f32x4 acc[4])
{
    union { bf16x8 v; unsigned u[4]; } pf;
#pragma unroll
    for (int wd = 0; wd < 4; ++wd) {
        f32x2 s;
        {
            const unsigned u0 = v00[wd];
            const f32x2 xv = { __builtin_bit_cast(float, u0 << 16),
                               __builtin_bit_cast(float, u0 & 0xffff0000u) };
            s = c00 * xv;
        }
        {
            const unsigned u0 = v01[wd];
            const f32x2 xv = { __builtin_bit_cast(float, u0 << 16),
                               __builtin_bit_cast(float, u0 & 0xffff0000u) };
            s += c01 * xv;
        }
        {
            const unsigned u0 = v10[wd];
            const f32x2 xv = { __builtin_bit_cast(float, u0 << 16),
                               __builtin_bit_cast(float, u0 & 0xffff0000u) };
            s += c10 * xv;
        }
        {
            const unsigned u0 = v11[wd];
            const f32x2 xv = { __builtin_bit_cast(float, u0 << 16),
                               __builtin_bit_cast(float, u0 & 0xffff0000u) };
            s += c11 * xv;
        }
        unsigned r;
        asm("v_cvt_pk_bf16_f32 %0, %1, %2" : "=v"(r) : "v"(s.x), "v"(s.y));
        pf.u[wd] = r;
    }
    acc[0] = __builtin_amdgcn_mfma_f32_16x16x32_bf16(wf0, pf.v, acc[0], 0, 0, 0);
    acc[1] = __builtin_amdgcn_mfma_f32_16x16x32_bf16(wf1, pf.v, acc[1], 0, 0, 0);
    acc[2] = __builtin_amdgcn_mfma_f32_16x16x32_bf16(wf2, pf.v, acc[2], 0, 0, 0);
    acc[3] = __builtin_amdgcn_mfma_f32_16x16x32_bf16(wf3, pf.v, acc[3], 0, 0, 0);
}

// ---------------------------------------------------------------------------
// Main kernel (4x16 tile, FULL-K WAVES — no channel split, no reduction):
// block = 4x16 output tile (1600 blocks), 4 waves = 4 rows; each wave
// computes its 16-px row over the full K=576 into acc[4] and stores
// directly (R26 lesson: strip-pairing doubled serial work and regressed;
// the reduction path itself costs a barrier + divergent epilogue + 8.7 KB
// LDS — deleted here). Staging amortizes 1.6x better (220 records / 64 px
// vs 176/32), single-pass (220 < 256 threads), NCHW f32 direct (R25).
// Hoisted separable geometry (R23-verified incl. >=0 checks).
// LDS = 31,680 B -> 4 blocks/CU at launch_bounds(256,4), ~16 waves/CU.
// ---------------------------------------------------------------------------
__global__ __launch_bounds__(256, 4) void pdconv_quad_kernel(
    const float* __restrict__ in,        // [B][CIN][H][W] f32 (original)
    const short* __restrict__ wtf,       // frag-ordered weights bf16
    const float* __restrict__ rate_map,  // [B][1][H][W] f32
    const float* __restrict__ bias,      // [COUT] f32
    float* __restrict__ out)             // [B][COUT][H][W] f32
{
    __shared__ short hin[HIN_SHORTS];    // 31,680 B

    const int tid  = threadIdx.x;
    const int wave = tid >> 6;
    const int lane = tid & 63;
    const int px   = lane & 15;
    const int g    = lane >> 4;

    // XCD-bijective swizzle (1600 % 8 == 0)
    const int cpx = gridDim.x >> 3;                     // 200
    const int bid = (blockIdx.x & 7) * cpx + (blockIdx.x >> 3);

    // bid -> (b, row-quad rr, col-block cc): 40 quads x 10 col-blocks / image
    const int b   = bid / 400;
    const int rem = bid - b * 400;
    const int rr  = rem / 10;
    const int cc  = rem - rr * 10;
    const int oy  = 4 * rr - 3;
    const int ox  = 16 * cc - 3;

    // ---- fused staging: NCHW f32 -> LDS bf16 halo (single pass) ----
    if (tid < RT * CT) {
        const int ty = tid / CT;
        const int tx = tid - ty * CT;
        const int gy = min(max(oy + ty, 0), HH - 1);
        const int gx = min(max(ox + tx, 0), WW - 1);
        const float* src = in + (size_t)b * CIN * HW + gy * WW + gx;
        short* dst = hin + tid * RS;
#pragma unroll 16
        for (int c = 0; c < CIN; ++c)
            dst[c] = f2bf(src[(size_t)c * HW]);
    }

    // ---- per-wave output row: row = 4rr + wave, cols 16cc..16cc+15 ----
    const int row = 4 * rr + wave;
    const int x   = 16 * cc + px;
    const float rate = rate_map[b * HW + row * WW + x];
    const float fy = (float)row, fx = (float)x;

    // ---- hoisted separable geometry (R23-verified incl. >=0 checks) ----
    float wy0v[3], wy1v[3];  int ryb[3];
#pragma unroll
    for (int ky = 0; ky < 3; ++ky) {
        const float sy  = fy + (float)(ky - 1) * rate;
        const float y0f = floorf(sy);
        const float wy  = sy - y0f;
        const int   y0  = (int)y0f;
        const float vy0 = (y0 >= 0 && y0 < HH) ? 1.0f : 0.0f;
        const float vy1 = (y0 + 1 >= 0 && y0 + 1 < HH) ? 1.0f : 0.0f;
        wy0v[ky] = (1.0f - wy) * vy0;
        wy1v[ky] = wy * vy1;
        ryb[ky]  = (y0 - oy) * (CT * RSB);               // tile-row byte offset
    }
    float wx0v[3], wx1v[3];  int txb[3];
#pragma unroll
    for (int kx = 0; kx < 3; ++kx) {
        const float sx  = fx + (float)(kx - 1) * rate;
        const float x0f = floorf(sx);
        const float wx  = sx - x0f;
        const int   x0  = (int)x0f;
        const float vx0 = (x0 >= 0 && x0 < WW) ? 1.0f : 0.0f;
        const float vx1 = (x0 + 1 >= 0 && x0 + 1 < WW) ? 1.0f : 0.0f;
        wx0v[kx] = (1.0f - wx) * vx0;
        wx1v[kx] = wx * vx1;
        txb[kx]  = (x0 - ox) * RSB;                      // tile-col byte offset
    }

    const int chan_off = 8 * g;                          // + 32*ks per half
    const short* wtb = wtf + lane * 8;                   // + frag*512

    f32x4 acc[4];
#pragma unroll
    for (int mt = 0; mt < 4; ++mt) acc[mt] = (f32x4){0.f, 0.f, 0.f, 0.f};

    __syncthreads();           // halo staged (only barrier in the kernel)

    // per tap: 2 K-halves x (4 ds_read_b128 + 4 weight frags + blend + MFMA)
#define DO_TAP(T) do {                                                       \
    const int ky = (T) / 3, kx = (T) - 3 * ((T) / 3);   /* constants */      \
    const float c00 = wy0v[ky] * wx0v[kx];                                   \
    const float c01 = wy0v[ky] * wx1v[kx];                                   \
    const float c10 = wy1v[ky] * wx0v[kx];                                   \
    const float c11 = wy1v[ky] * wx1v[kx];                                   \
    const short* hb = (const short*)((const char*)hin + ryb[ky] + txb[kx])   \
                      + chan_off;                                            \
    _Pragma("unroll")                                                        \
    for (int ks = 0; ks < 2; ++ks) {                                         \
        const short* hk = hb + 32 * ks;                                      \
        const u32x4 v00 = *(const u32x4*)(hk);                               \
        const u32x4 v01 = *(const u32x4*)(hk + RS);                          \
        const u32x4 v10 = *(const u32x4*)(hk + CT * RS);                     \
        const u32x4 v11 = *(const u32x4*)(hk + (CT + 1) * RS);               \
        const short* wb = wtb + (size_t)(((T) * 2 + ks) * 4) * 512;          \
        const bf16x8 wf0 = *(const bf16x8*)(wb);                             \
        const bf16x8 wf1 = *(const bf16x8*)(wb + 512);                       \
        const bf16x8 wf2 = *(const bf16x8*)(wb + 1024);                      \
        const bf16x8 wf3 = *(const bf16x8*)(wb + 1536);                      \
        consume_tap(v00, v01, v10, v11, c00, c01, c10, c11,                  \
                    wf0, wf1, wf2, wf3, acc);                                \
    }                                                                        \
} while (0)

    DO_TAP(0); DO_TAP(1); DO_TAP(2); DO_TAP(3); DO_TAP(4);
    DO_TAP(5); DO_TAP(6); DO_TAP(7); DO_TAP(8);
#undef DO_TAP

    // ---- direct epilogue: every wave stores its own row ----
    float* op = out + (size_t)b * COUT * HW + row * WW + 16 * cc + px;
#pragma unroll
    for (int mt = 0; mt < 4; ++mt) {
        const f32x4 bv = *(const f32x4*)(bias + 16 * mt + 4 * g);
#pragma unroll
        for (int j = 0; j < 4; ++j) {
            const int o = 16 * mt + 4 * g + j;
            op[(size_t)o * HW] = acc[mt][j] + bv[j];
        }
    }
}

// ---------------------------------------------------------------------------
// Fallback (round-7 NCHW path) if ws_size is too small.
// ---------------------------------------------------------------------------
__global__ void wt2_kernel(const float* __restrict__ w, short* __restrict__ wt2) {
    int i = blockIdx.x * 256 + threadIdx.x;
    if (i < 9 * COUT * CIN) {
        int c = i & 63, o = (i >> 6) & 63, t = i >> 12;
        wt2[i] = f2bf(w[(o * CIN + c) * 9 + t]);
    }
}

__global__ __launch_bounds__(256) void pdconv_mfma_kernel(
    const float* __restrict__ in, const short* __restrict__ wt2,
    const float* __restrict__ rate_map, const float* __restrict__ bias,
    float* __restrict__ out)
{
    const int tid = threadIdx.x, wave = tid >> 6, lane = tid & 63;
    const int px = lane & 15, g = lane >> 4;
    const int cpx = gridDim.x >> 3;
    const int bid = (blockIdx.x & 7) * cpx + (blockIdx.x >> 3);
    const int base = bid * 64 + wave * 16;
    const int b = base / HW, pix0 = base - b * HW;
    const int y = pix0 / WW, x0 = pix0 - y * WW, x = x0 + px;
    const float rate = rate_map[base + px];
    const float fy = (float)y, fx = (float)x;
    f32x4 acc[4];
#pragma unroll
    for (int mt = 0; mt < 4; ++mt) acc[mt] = (f32x4){0.f, 0.f, 0.f, 0.f};
    const float* img  = in + (size_t)b * CIN * HW;
    const float* imgg = img + (size_t)g * 8 * HW;
#pragma unroll 1
    for (int t = 0; t < 9; ++t) {
        const int ky = t / 3, kx = t - 3 * ky;
        const float sy = fy + (float)(ky - 1) * rate;
        const float sx = fx + (float)(kx - 1) * rate;
        const float y0f = floorf(sy), x0f = floorf(sx);
        const float wy = sy - y0f, wx = sx - x0f;
        const int y0 = (int)y0f, x0i = (int)x0f, y1 = y0 + 1, x1 = x0i + 1;
        const float omwy = 1.0f - wy, omwx = 1.0f - wx;
        const float vy0 = (y0 >= 0 && y0 < HH) ? 1.0f : 0.0f;
        const float vy1 = (y1 >= 0 && y1 < HH) ? 1.0f : 0.0f;
        const float vx0 = (x0i >= 0 && x0i < WW) ? 1.0f : 0.0f;
        const float vx1 = (x1 >= 0 && x1 < WW) ? 1.0f : 0.0f;
        const float c00 = omwy * omwx * vy0 * vx0, c01 = omwy * wx * vy0 * vx1;
        const float c10 = wy * omwx * vy1 * vx0,  c11 = wy * wx * vy1 * vx1;
        const int cy0 = min(max(y0, 0), HH - 1), cy1 = min(max(y1, 0), HH - 1);
        const int cx0 = min(max(x0i, 0), WW - 1), cx1 = min(max(x1, 0), WW - 1);
        const int i00 = cy0 * WW + cx0, i01 = cy0 * WW + cx1;
        const int i10 = cy1 * WW + cx0, i11 = cy1 * WW + cx1;
#pragma unroll
        for (int ks = 0; ks < 2; ++ks) {
            bf16x8 wf[4];
#pragma unroll
            for (int mt = 0; mt < 4; ++mt)
                wf[mt] = *(const bf16x8*)(wt2 +
                          ((t * COUT + 16 * mt + px) * CIN + 32 * ks + 8 * g));
            float a[8];
#pragma unroll
            for (int j = 0; j < 8; ++j) {
                const float* ch = imgg + (size_t)(32 * ks + j) * HW;
                a[j] = c00 * ch[i00] + c01 * ch[i01] + c10 * ch[i10] + c11 * ch[i11];
            }
            union { bf16x8 v; short s[8]; } pf;
#pragma unroll
            for (int j = 0; j < 8; ++j) pf.s[j] = f2bf(a[j]);
#pragma unroll
            for (int mt = 0; mt < 4; ++mt)
                acc[mt] = __builtin_amdgcn_mfma_f32_16x16x32_bf16(
                              wf[mt], pf.v, acc[mt], 0, 0, 0);
        }
    }
    float* op = out + (size_t)b * COUT * HW + pix0 + px;
#pragma unroll
    for (int mt = 0; mt < 4; ++mt)
#pragma unroll
        for (int r = 0; r < 4; ++r) {
            const int o = 16 * mt + 4 * g + r;
            op[(size_t)o * HW] = acc[mt][r] + bias[o];
        }
}

extern "C" void kernel_launch(void* const* d_in, const int* in_sizes, int n_in,
                              void* d_out, int out_size, void* d_ws, size_t ws_size,
                              hipStream_t stream) {
    (void)in_sizes; (void)n_in; (void)out_size;
    const float* in   = (const float*)d_in[0];
    const float* w    = (const float*)d_in[1];
    const float* rm   = (const float*)d_in[2];
    const float* bias = (const float*)d_in[3];
    float* out = (float*)d_out;

    const size_t WTF_BYTES = 36864 * sizeof(short);   // 73,728

    if (ws_size >= WTF_BYTES) {
        short* wtf = (short*)d_ws;
        hipLaunchKernelGGL(wtf_kernel, dim3(144), dim3(256), 0, stream, w, wtf);
        const int nblocks = NB * 40 * 10;  // 1600: 4x16 tiles
        hipLaunchKernelGGL(pdconv_quad_kernel, dim3(nblocks), dim3(256), 0,
                           stream, in, wtf, rm, bias, out);
    } else {
        short* wt2 = (short*)d_ws;   // 73,728 B
        hipLaunchKernelGGL(wt2_kernel, dim3(144), dim3(256), 0, stream, w, wt2);
        hipLaunchKernelGGL(pdconv_mfma_kernel, dim3((NB * HW) / 64), dim3(256),
                           0, stream, in, wt2, rm, bias, out);
    }
}

// Round 29
// 41.520 us; speedup vs baseline: 1.1262x; 1.0094x over previous
//
#include <hip/hip_runtime.h>
#include <hip/hip_bf16.h>

#define NB   4
#define CIN  64
#define COUT 64
#define HH   160
#define WW   160
#define HW   (HH * WW)

// halo tile: 4x16 output tile, rate in [1,3) =>
// rows 4rr-3 .. 4rr+6 (10), cols 16cc-3 .. 16cc+18 (22).
#define RT   10
#define CT   22
#define RS   72              // record stride in shorts (144 B: 64ch + 8 pad)
#define RSB  (RS * 2)        // record stride in bytes (144)
#define HIN_SHORTS (RT * CT * RS)   // 15840 shorts = 31680 B

typedef __attribute__((ext_vector_type(8))) short bf16x8;   // 8 bf16 = 4 VGPR
typedef __attribute__((ext_vector_type(4))) float f32x4;
typedef __attribute__((ext_vector_type(2))) float f32x2;
typedef __attribute__((ext_vector_type(4))) unsigned int u32x4;

static __device__ __forceinline__ short f2bf(float v) {
    return __builtin_bit_cast(short, __float2bfloat16(v));
}

// ---------------------------------------------------------------------------
// Pre-pass: weight [O][C][3][3] f32 -> wtf in exact A-fragment order:
// wtf[t][ks][mt][lane][j]; frag (t,ks,mt) = contiguous 1 KB, lane reads 16 B.
// ---------------------------------------------------------------------------
__global__ void wtf_kernel(const float* __restrict__ w, short* __restrict__ wtf) {
    int i = blockIdx.x * 256 + threadIdx.x;   // 9*2*4*64*8 = 36864
    if (i < 36864) {
        const int j  = i & 7;
        const int l  = (i >> 3) & 63;
        const int mt = (i >> 9) & 3;
        const int ks = (i >> 11) & 1;
        const int t  = i >> 12;
        const int o  = 16 * mt + (l & 15);
        const int c  = 32 * ks + 8 * (l >> 4) + j;
        wtf[i] = f2bf(w[(o * CIN + c) * 9 + t]);
    }
}

// Blend 8 channels (4 dwords of packed bf16 pairs) + 4 MFMA rank-updates.
static __device__ __forceinline__ void consume_tap(
    const u32x4 v00, const u32x4 v01, const u32x4 v10, const u32x4 v11,
    const float c00, const float c01, const float c10, const float c11,
    const bf16x8 wf0, const bf16x8 wf1, const bf16x8 wf2, const bf16x8 wf3,
    f32x4 acc[4])
{
    union { bf16x8 v; unsigned u[4]; } pf;
#pragma unroll
    for (int wd = 0; wd < 4; ++wd) {
        f32x2 s;
        {
            const unsigned u0 = v00[wd];
            const f32x2 xv = { __builtin_bit_cast(float, u0 << 16),
                               __builtin_bit_cast(float, u0 & 0xffff0000u) };
            s = c00 * xv;
        }
        {
            const unsigned u0 = v01[wd];
            const f32x2 xv = { __builtin_bit_cast(float, u0 << 16),
                               __builtin_bit_cast(float, u0 & 0xffff0000u) };
            s += c01 * xv;
        }
        {
            const unsigned u0 = v10[wd];
            const f32x2 xv = { __builtin_bit_cast(float, u0 << 16),
                               __builtin_bit_cast(float, u0 & 0xffff0000u) };
            s += c10 * xv;
        }
        {
            const unsigned u0 = v11[wd];
            const f32x2 xv = { __builtin_bit_cast(float, u0 << 16),
                               __builtin_bit_cast(float, u0 & 0xffff0000u) };
            s += c11 * xv;
        }
        unsigned r;
        asm("v_cvt_pk_bf16_f32 %0, %1, %2" : "=v"(r) : "v"(s.x), "v"(s.y));
        pf.u[wd] = r;
    }
    acc[0] = __builtin_amdgcn_mfma_f32_16x16x32_bf16(wf0, pf.v, acc[0], 0, 0, 0);
    acc[1] = __builtin_amdgcn_mfma_f32_16x16x32_bf16(wf1, pf.v, acc[1], 0, 0, 0);
    acc[2] = __builtin_amdgcn_mfma_f32_16x16x32_bf16(wf2, pf.v, acc[2], 0, 0, 0);
    acc[3] = __builtin_amdgcn_mfma_f32_16x16x32_bf16(wf3, pf.v, acc[3], 0, 0, 0);
}

// ---------------------------------------------------------------------------
// Main kernel (4x16 tile, FULL-K WAVES — no channel split, no reduction):
// block = 4x16 output tile (1600 blocks), 4 waves = 4 rows; each wave
// computes its 16-px row over the full K=576 into acc[4] and stores
// directly. Fused NCHW staging (R25), hoisted separable geometry (R23).
// R28's conflict-break attempt (136 B stride + 8 B reads) failed
// correctness (suspected LLVM merge to misaligned ds_read_b128) — this is
// the R27-proven version, best measured at 41.9 us.
// LDS = 31,680 B -> 4 blocks/CU at launch_bounds(256,4).
// ---------------------------------------------------------------------------
__global__ __launch_bounds__(256, 4) void pdconv_quad_kernel(
    const float* __restrict__ in,        // [B][CIN][H][W] f32 (original)
    const short* __restrict__ wtf,       // frag-ordered weights bf16
    const float* __restrict__ rate_map,  // [B][1][H][W] f32
    const float* __restrict__ bias,      // [COUT] f32
    float* __restrict__ out)             // [B][COUT][H][W] f32
{
    __shared__ short hin[HIN_SHORTS];    // 31,680 B

    const int tid  = threadIdx.x;
    const int wave = tid >> 6;
    const int lane = tid & 63;
    const int px   = lane & 15;
    const int g    = lane >> 4;

    // XCD-bijective swizzle (1600 % 8 == 0)
    const int cpx = gridDim.x >> 3;                     // 200
    const int bid = (blockIdx.x & 7) * cpx + (blockIdx.x >> 3);

    // bid -> (b, row-quad rr, col-block cc): 40 quads x 10 col-blocks / image
    const int b   = bid / 400;
    const int rem = bid - b * 400;
    const int rr  = rem / 10;
    const int cc  = rem - rr * 10;
    const int oy  = 4 * rr - 3;
    const int ox  = 16 * cc - 3;

    // ---- fused staging: NCHW f32 -> LDS bf16 halo (single pass) ----
    if (tid < RT * CT) {
        const int ty = tid / CT;
        const int tx = tid - ty * CT;
        const int gy = min(max(oy + ty, 0), HH - 1);
        const int gx = min(max(ox + tx, 0), WW - 1);
        const float* src = in + (size_t)b * CIN * HW + gy * WW + gx;
        short* dst = hin + tid * RS;
#pragma unroll 16
        for (int c = 0; c < CIN; ++c)
            dst[c] = f2bf(src[(size_t)c * HW]);
    }

    // ---- per-wave output row: row = 4rr + wave, cols 16cc..16cc+15 ----
    const int row = 4 * rr + wave;
    const int x   = 16 * cc + px;
    const float rate = rate_map[b * HW + row * WW + x];
    const float fy = (float)row, fx = (float)x;

    // ---- hoisted separable geometry (R23-verified incl. >=0 checks) ----
    float wy0v[3], wy1v[3];  int ryb[3];
#pragma unroll
    for (int ky = 0; ky < 3; ++ky) {
        const float sy  = fy + (float)(ky - 1) * rate;
        const float y0f = floorf(sy);
        const float wy  = sy - y0f;
        const int   y0  = (int)y0f;
        const float vy0 = (y0 >= 0 && y0 < HH) ? 1.0f : 0.0f;
        const float vy1 = (y0 + 1 >= 0 && y0 + 1 < HH) ? 1.0f : 0.0f;
        wy0v[ky] = (1.0f - wy) * vy0;
        wy1v[ky] = wy * vy1;
        ryb[ky]  = (y0 - oy) * (CT * RSB);               // tile-row byte offset
    }
    float wx0v[3], wx1v[3];  int txb[3];
#pragma unroll
    for (int kx = 0; kx < 3; ++kx) {
        const float sx  = fx + (float)(kx - 1) * rate;
        const float x0f = floorf(sx);
        const float wx  = sx - x0f;
        const int   x0  = (int)x0f;
        const float vx0 = (x0 >= 0 && x0 < WW) ? 1.0f : 0.0f;
        const float vx1 = (x0 + 1 >= 0 && x0 + 1 < WW) ? 1.0f : 0.0f;
        wx0v[kx] = (1.0f - wx) * vx0;
        wx1v[kx] = wx * vx1;
        txb[kx]  = (x0 - ox) * RSB;                      // tile-col byte offset
    }

    const int chan_off = 8 * g;                          // + 32*ks per half
    const short* wtb = wtf + lane * 8;                   // + frag*512

    f32x4 acc[4];
#pragma unroll
    for (int mt = 0; mt < 4; ++mt) acc[mt] = (f32x4){0.f, 0.f, 0.f, 0.f};

    __syncthreads();           // halo staged (only barrier in the kernel)

    // per tap: 2 K-halves x (4 ds_read_b128 + 4 weight frags + blend + MFMA)
#define DO_TAP(T) do {                                                       \
    const int ky = (T) / 3, kx = (T) - 3 * ((T) / 3);   /* constants */      \
    const float c00 = wy0v[ky] * wx0v[kx];                                   \
    const float c01 = wy0v[ky] * wx1v[kx];                                   \
    const float c10 = wy1v[ky] * wx0v[kx];                                   \
    const float c11 = wy1v[ky] * wx1v[kx];                                   \
    const short* hb = (const short*)((const char*)hin + ryb[ky] + txb[kx])   \
                      + chan_off;                                            \
    _Pragma("unroll")                                                        \
    for (int ks = 0; ks < 2; ++ks) {                                         \
        const short* hk = hb + 32 * ks;                                      \
        const u32x4 v00 = *(const u32x4*)(hk);                               \
        const u32x4 v01 = *(const u32x4*)(hk + RS);                          \
        const u32x4 v10 = *(const u32x4*)(hk + CT * RS);                     \
        const u32x4 v11 = *(const u32x4*)(hk + (CT + 1) * RS);               \
        const short* wb = wtb + (size_t)(((T) * 2 + ks) * 4) * 512;          \
        const bf16x8 wf0 = *(const bf16x8*)(wb);                             \
        const bf16x8 wf1 = *(const bf16x8*)(wb + 512);                       \
        const bf16x8 wf2 = *(const bf16x8*)(wb + 1024);                      \
        const bf16x8 wf3 = *(const bf16x8*)(wb + 1536);                      \
        consume_tap(v00, v01, v10, v11, c00, c01, c10, c11,                  \
                    wf0, wf1, wf2, wf3, acc);                                \
    }                                                                        \
} while (0)

    DO_TAP(0); DO_TAP(1); DO_TAP(2); DO_TAP(3); DO_TAP(4);
    DO_TAP(5); DO_TAP(6); DO_TAP(7); DO_TAP(8);
#undef DO_TAP

    // ---- direct epilogue: every wave stores its own row ----
    float* op = out + (size_t)b * COUT * HW + row * WW + 16 * cc + px;
#pragma unroll
    for (int mt = 0; mt < 4; ++mt) {
        const f32x4 bv = *(const f32x4*)(bias + 16 * mt + 4 * g);
#pragma unroll
        for (int j = 0; j < 4; ++j) {
            const int o = 16 * mt + 4 * g + j;
            op[(size_t)o * HW] = acc[mt][j] + bv[j];
        }
    }
}

// ---------------------------------------------------------------------------
// Fallback (round-7 NCHW path) if ws_size is too small.
// ---------------------------------------------------------------------------
__global__ void wt2_kernel(const float* __restrict__ w, short* __restrict__ wt2) {
    int i = blockIdx.x * 256 + threadIdx.x;
    if (i < 9 * COUT * CIN) {
        int c = i & 63, o = (i >> 6) & 63, t = i >> 12;
        wt2[i] = f2bf(w[(o * CIN + c) * 9 + t]);
    }
}

__global__ __launch_bounds__(256) void pdconv_mfma_kernel(
    const float* __restrict__ in, const short* __restrict__ wt2,
    const float* __restrict__ rate_map, const float* __restrict__ bias,
    float* __restrict__ out)
{
    const int tid = threadIdx.x, wave = tid >> 6, lane = tid & 63;
    const int px = lane & 15, g = lane >> 4;
    const int cpx = gridDim.x >> 3;
    const int bid = (blockIdx.x & 7) * cpx + (blockIdx.x >> 3);
    const int base = bid * 64 + wave * 16;
    const int b = base / HW, pix0 = base - b * HW;
    const int y = pix0 / WW, x0 = pix0 - y * WW, x = x0 + px;
    const float rate = rate_map[base + px];
    const float fy = (float)y, fx = (float)x;
    f32x4 acc[4];
#pragma unroll
    for (int mt = 0; mt < 4; ++mt) acc[mt] = (f32x4){0.f, 0.f, 0.f, 0.f};
    const float* img  = in + (size_t)b * CIN * HW;
    const float* imgg = img + (size_t)g * 8 * HW;
#pragma unroll 1
    for (int t = 0; t < 9; ++t) {
        const int ky = t / 3, kx = t - 3 * ky;
        const float sy = fy + (float)(ky - 1) * rate;
        const float sx = fx + (float)(kx - 1) * rate;
        const float y0f = floorf(sy), x0f = floorf(sx);
        const float wy = sy - y0f, wx = sx - x0f;
        const int y0 = (int)y0f, x0i = (int)x0f, y1 = y0 + 1, x1 = x0i + 1;
        const float omwy = 1.0f - wy, omwx = 1.0f - wx;
        const float vy0 = (y0 >= 0 && y0 < HH) ? 1.0f : 0.0f;
        const float vy1 = (y1 >= 0 && y1 < HH) ? 1.0f : 0.0f;
        const float vx0 = (x0i >= 0 && x0i < WW) ? 1.0f : 0.0f;
        const float vx1 = (x1 >= 0 && x1 < WW) ? 1.0f : 0.0f;
        const float c00 = omwy * omwx * vy0 * vx0, c01 = omwy * wx * vy0 * vx1;
        const float c10 = wy * omwx * vy1 * vx0,  c11 = wy * wx * vy1 * vx1;
        const int cy0 = min(max(y0, 0), HH - 1), cy1 = min(max(y1, 0), HH - 1);
        const int cx0 = min(max(x0i, 0), WW - 1), cx1 = min(max(x1, 0), WW - 1);
        const int i00 = cy0 * WW + cx0, i01 = cy0 * WW + cx1;
        const int i10 = cy1 * WW + cx0, i11 = cy1 * WW + cx1;
#pragma unroll
        for (int ks = 0; ks < 2; ++ks) {
            bf16x8 wf[4];
#pragma unroll
            for (int mt = 0; mt < 4; ++mt)
                wf[mt] = *(const bf16x8*)(wt2 +
                          ((t * COUT + 16 * mt + px) * CIN + 32 * ks + 8 * g));
            float a[8];
#pragma unroll
            for (int j = 0; j < 8; ++j) {
                const float* ch = imgg + (size_t)(32 * ks + j) * HW;
                a[j] = c00 * ch[i00] + c01 * ch[i01] + c10 * ch[i10] + c11 * ch[i11];
            }
            union { bf16x8 v; short s[8]; } pf;
#pragma unroll
            for (int j = 0; j < 8; ++j) pf.s[j] = f2bf(a[j]);
#pragma unroll
            for (int mt = 0; mt < 4; ++mt)
                acc[mt] = __builtin_amdgcn_mfma_f32_16x16x32_bf16(
                              wf[mt], pf.v, acc[mt], 0, 0, 0);
        }
    }
    float* op = out + (size_t)b * COUT * HW + pix0 + px;
#pragma unroll
    for (int mt = 0; mt < 4; ++mt)
#pragma unroll
        for (int r = 0; r < 4; ++r) {
            const int o = 16 * mt + 4 * g + r;
            op[(size_t)o * HW] = acc[mt][r] + bias[o];
        }
}

extern "C" void kernel_launch(void* const* d_in, const int* in_sizes, int n_in,
                              void* d_out, int out_size, void* d_ws, size_t ws_size,
                              hipStream_t stream) {
    (void)in_sizes; (void)n_in; (void)out_size;
    const float* in   = (const float*)d_in[0];
    const float* w    = (const float*)d_in[1];
    const float* rm   = (const float*)d_in[2];
    const float* bias = (const float*)d_in[3];
    float* out = (float*)d_out;

    const size_t WTF_BYTES = 36864 * sizeof(short);   // 73,728

    if (ws_size >= WTF_BYTES) {
        short* wtf = (short*)d_ws;
        hipLaunchKernelGGL(wtf_kernel, dim3(144), dim3(256), 0, stream, w, wtf);
        const int nblocks = NB * 40 * 10;  // 1600: 4x16 tiles
        hipLaunchKernelGGL(pdconv_quad_kernel, dim3(nblocks), dim3(256), 0,
                           stream, in, wtf, rm, bias, out);
    } else {
        short* wt2 = (short*)d_ws;   // 73,728 B
        hipLaunchKernelGGL(wt2_kernel, dim3(144), dim3(256), 0, stream, w, wt2);
        hipLaunchKernelGGL(pdconv_mfma_kernel, dim3((NB * HW) / 64), dim3(256),
                           0, stream, in, wt2, rm, bias, out);
    }
}